// Round 9
// baseline (2575.114 us; speedup 1.0000x reference)
//
#include <hip/hip_runtime.h>

#define NN 100000
#define NE 1600000
#define NP 200000
#define CH 128
#define LK 264    // padded LDS row stride (fp16 elems)

#define BSH 6                    // 64 nodes per bucket
#define NB  1563                 // ceil(NN / 64)
#define G1  256                  // hist/scatter grid
#define EPB (NE / G1)            // 6250 edges per block
#define NCAST 6250               // cast blocks: NN*CH/8 / 256

typedef _Float16 f16x8 __attribute__((ext_vector_type(8)));
typedef _Float16 f16x4 __attribute__((ext_vector_type(4)));
typedef _Float16 h2 __attribute__((ext_vector_type(2)));
typedef float f32x4 __attribute__((ext_vector_type(4)));

// ---- fused prep: [0,NCAST) cast x->fp16 | [NCAST,NCAST+G1) bucket hist | rest: weight prep ----
__global__ __launch_bounds__(256)
void fused_prep_kernel(const float* __restrict__ x, _Float16* __restrict__ xh,
                       const int* __restrict__ dst, int* __restrict__ hist,
                       const float* __restrict__ w1r, const float* __restrict__ w1o,
                       const float* __restrict__ w2r, const float* __restrict__ w2o,
                       _Float16* __restrict__ w1t, _Float16* __restrict__ w2t) {
    __shared__ int s_h[NB];
    const int bb = blockIdx.x, tid = threadIdx.x;
    if (bb < NCAST) {
        int i = bb * 256 + tid;   // i < 1.6M exactly
        const float4* p = (const float4*)x + (size_t)i * 2;
        float4 a = p[0], b = p[1];
        f16x8 o = { (_Float16)a.x, (_Float16)a.y, (_Float16)a.z, (_Float16)a.w,
                    (_Float16)b.x, (_Float16)b.y, (_Float16)b.z, (_Float16)b.w };
        *((f16x8*)xh + i) = o;
    } else if (bb < NCAST + G1) {
        int g = bb - NCAST;
        for (int i = tid; i < NB; i += 256) s_h[i] = 0;
        __syncthreads();
        int start = g * EPB, end = start + EPB;
        for (int e = start + tid; e < end; e += 256)
            atomicAdd(&s_h[dst[e] >> BSH], 1);
        __syncthreads();
        int* row = hist + (size_t)g * NB;
        for (int i = tid; i < NB; i += 256) row[i] = s_h[i];
    } else {
        int idx = (bb - NCAST - G1) * 256 + tid;   // < 65536
        int which = idx >> 15;
        int li = idx & 32767;
        int n = li >> 8, k = li & 255;
        const float* wr = which ? w2r : w1r;
        const float* wo = which ? w2o : w1o;
        _Float16* wt = which ? w2t : w1t;
        float v = (k < 128) ? wr[k * 128 + n] : wo[(k - 128) * 128 + n];
        wt[li] = (_Float16)v;
    }
}

// ---- column exclusive scan over g — one wave per bucket ----
__global__ __launch_bounds__(256)
void colscan_kernel(int* __restrict__ hist, int* __restrict__ totals) {
    int b = blockIdx.x * 4 + (threadIdx.x >> 6);
    if (b >= NB) return;
    int lane = threadIdx.x & 63;
    size_t base = (size_t)(lane * 4) * NB + b;
    int v0 = hist[base];
    int v1 = hist[base + NB];
    int v2 = hist[base + 2 * (size_t)NB];
    int v3 = hist[base + 3 * (size_t)NB];
    int s0 = v0, s1 = s0 + v1, s2 = s1 + v2, s3 = s2 + v3;
    int incl = s3;
#pragma unroll
    for (int off = 1; off < 64; off <<= 1) {
        int n = __shfl_up(incl, off, 64);
        if (lane >= off) incl += n;
    }
    int excl = incl - s3;
    hist[base] = excl;
    hist[base + NB] = excl + s0;
    hist[base + 2 * (size_t)NB] = excl + s1;
    hist[base + 3 * (size_t)NB] = excl + s2;
    if (lane == 63) totals[b] = incl;
}

// ---- exclusive scan of bucket totals -> base[NB+1] ----
__global__ __launch_bounds__(1024)
void scanB_kernel(const int* __restrict__ totals, int* __restrict__ base) {
    __shared__ int s[2048];
    int tid = threadIdx.x;
    for (int i = tid; i < 2048; i += 1024) s[i] = (i < NB) ? totals[i] : 0;
    __syncthreads();
    for (int off = 1; off < 2048; off <<= 1) {
        int i0 = tid, i1 = tid + 1024;
        int v0 = (i0 >= off) ? s[i0 - off] : 0;
        int v1 = (i1 >= off) ? s[i1 - off] : 0;
        __syncthreads();
        s[i0] += v0; s[i1] += v1;
        __syncthreads();
    }
    if (tid == 0) base[0] = 0;
    for (int i = tid; i < NB; i += 1024) base[i + 1] = s[i];
}

// ---- scatter edges into bucket regions; x = src | dst_local<<17, y = fp32 weight ----
__global__ __launch_bounds__(256)
void bucket_scatter_kernel(const int* __restrict__ src, const int* __restrict__ dst,
                           const float* __restrict__ ew, const int* __restrict__ hist,
                           const int* __restrict__ base, int2* __restrict__ tmp) {
    __shared__ int s_cur[NB];
    const int* row = hist + (size_t)blockIdx.x * NB;
    for (int i = threadIdx.x; i < NB; i += 256) s_cur[i] = base[i] + row[i];
    __syncthreads();
    int start = blockIdx.x * EPB, end = start + EPB;
    for (int e = start + threadIdx.x; e < end; e += 256) {
        int d = dst[e];
        int b = d >> BSH;
        int pos = atomicAdd(&s_cur[b], 1);
        tmp[pos] = make_int2(src[e] | ((d & 63) << 17), __float_as_int(ew[e]));
    }
}

// ---- MEGA: per bucket (64 nodes) — gather into LDS acc + mean + MFMA layer ----
// feat is BOTH the neighbor source and the root (self) source.
template <bool RELU>
__global__ __launch_bounds__(256)
void mega_kernel(const int2* __restrict__ tmp, const int* __restrict__ base,
                 const _Float16* __restrict__ feat, const _Float16* __restrict__ wt,
                 const float* __restrict__ bias, _Float16* __restrict__ out, int N) {
    __shared__ __align__(16) char s_raw[64 * LK * 2];   // 33792 B: acc fp32[64][128] then atile fp16[64][LK]
    __shared__ int s_deg[64];
    float (*acc)[CH] = (float(*)[CH])s_raw;
    _Float16 (*atile)[LK] = (_Float16(*)[LK])s_raw;

    const int b = blockIdx.x;
    const int lo = base[b], hi = base[b + 1];
    const int nbase = b << BSH;
    const int tid = threadIdx.x;

    // zero acc + deg
    {
        float4 z4 = make_float4(0.f, 0.f, 0.f, 0.f);
        float4* p = (float4*)s_raw;
        for (int i = tid; i < 64 * CH / 4; i += 256) p[i] = z4;
        if (tid < 64) s_deg[tid] = 0;
    }
    __syncthreads();

    // ---- phase 1: edge gather, quarter-wave per edge, LDS f32 atomics ----
    {
        const int qg = tid >> 4;          // 16 quarters
        const int l16 = tid & 15;
        const int c8 = l16 << 3;
        int i = lo + qg;
        if (i < hi) {
            int2 e = tmp[i];
            f16x8 v = *(const f16x8*)&feat[(size_t)(e.x & 0x1FFFF) * CH + c8];
            for (i += 16; i < hi; i += 16) {
                int2 e2 = tmp[i];
                f16x8 v2 = *(const f16x8*)&feat[(size_t)(e2.x & 0x1FFFF) * CH + c8];
                int dl = (e.x >> 17) & 63;
                float w = __int_as_float(e.y);
                if (l16 == 0) atomicAdd(&s_deg[dl], 1);
#pragma unroll
                for (int j = 0; j < 8; j++) atomicAdd(&acc[dl][c8 + j], w * (float)v[j]);
                e = e2; v = v2;
            }
            int dl = (e.x >> 17) & 63;
            float w = __int_as_float(e.y);
            if (l16 == 0) atomicAdd(&s_deg[dl], 1);
#pragma unroll
            for (int j = 0; j < 8; j++) atomicAdd(&acc[dl][c8 + j], w * (float)v[j]);
        }
    }
    __syncthreads();

    // ---- phase 2: mean + fp16 repack in place (reg-staged), plus self-row load ----
    {
        const int n = tid >> 2;            // 4 threads per row
        const int c32 = (tid & 3) << 5;    // 32 channels each
        const int gn = nbase + n;
        float vals[32];
#pragma unroll
        for (int j = 0; j < 32; j += 4) {
            float4 t4 = *(const float4*)&acc[n][c32 + j];
            vals[j] = t4.x; vals[j + 1] = t4.y; vals[j + 2] = t4.z; vals[j + 3] = t4.w;
        }
        f16x8 xv[4] = {};
        if (gn < N) {
#pragma unroll
            for (int j = 0; j < 4; j++)
                xv[j] = *(const f16x8*)&feat[(size_t)gn * CH + c32 + j * 8];
        }
        float inv = 1.0f / fmaxf((float)s_deg[n], 1.0f);
        __syncthreads();   // all acc reads complete before overwrite
#pragma unroll
        for (int j = 0; j < 32; j += 2) {
            h2 p = { (_Float16)(vals[j] * inv), (_Float16)(vals[j + 1] * inv) };
            *(h2*)&atile[n][c32 + j] = p;
        }
#pragma unroll
        for (int j = 0; j < 4; j++)
            *(f16x8*)&atile[n][128 + c32 + j * 8] = xv[j];
    }
    __syncthreads();

    // ---- phase 3: MFMA layer 64x128 = [agg|self] @ Wt^T + b ----
    const int wave = tid >> 6;
    const int lane = tid & 63;
    const int quad = lane >> 4;
    const int l16  = lane & 15;

    f32x4 ac[4][2];
#pragma unroll
    for (int m = 0; m < 4; m++)
#pragma unroll
        for (int t = 0; t < 2; t++) ac[m][t] = (f32x4){0.f, 0.f, 0.f, 0.f};

    const int kq = quad * 8;
#pragma unroll
    for (int ks = 0; ks < 8; ks++) {
        int kbase = ks * 32 + kq;
        f16x8 bf[2];
#pragma unroll
        for (int t = 0; t < 2; t++) {
            int n = wave * 32 + t * 16 + l16;
            bf[t] = *(const f16x8*)&wt[(size_t)n * 256 + kbase];
        }
#pragma unroll
        for (int m = 0; m < 4; m++) {
            f16x8 af = *(const f16x8*)&atile[m * 16 + l16][kbase];
            ac[m][0] = __builtin_amdgcn_mfma_f32_16x16x32_f16(af, bf[0], ac[m][0], 0, 0, 0);
            ac[m][1] = __builtin_amdgcn_mfma_f32_16x16x32_f16(af, bf[1], ac[m][1], 0, 0, 0);
        }
    }

    float bv[2];
    bv[0] = bias[wave * 32 + l16];
    bv[1] = bias[wave * 32 + 16 + l16];

#pragma unroll
    for (int m = 0; m < 4; m++) {
#pragma unroll
        for (int r = 0; r < 4; r++) {
            int node = nbase + m * 16 + quad * 4 + r;
            if (node >= N) continue;
#pragma unroll
            for (int t = 0; t < 2; t++) {
                float v = ac[m][t][r] + bv[t];
                if (RELU) v = fmaxf(v, 0.f);
                out[(size_t)node * CH + wave * 32 + t * 16 + l16] = (_Float16)v;
            }
        }
    }
}

// ---- decode: half-wave per pair, f16x4 per lane ----
__global__ void decode_kernel(const _Float16* __restrict__ z,
                              const int* __restrict__ ps,
                              const int* __restrict__ pd,
                              float* __restrict__ out, int P) {
    long tid = (long)blockIdx.x * blockDim.x + threadIdx.x;
    int p = (int)(tid >> 5);
    int lane = (int)(tid & 31);
    if (p >= P) return;
    int s = ps[p], d = pd[p];
    f16x4 a = *(const f16x4*)&z[(size_t)s * CH + lane * 4];
    f16x4 b = *(const f16x4*)&z[(size_t)d * CH + lane * 4];
    float v = (float)a[0] * (float)b[0] + (float)a[1] * (float)b[1]
            + (float)a[2] * (float)b[2] + (float)a[3] * (float)b[3];
#pragma unroll
    for (int off = 16; off > 0; off >>= 1) v += __shfl_xor(v, off, 64);
    if (lane == 0) out[p] = v * 0.08838834764831845f;  // 1/sqrt(128)
}

extern "C" void kernel_launch(void* const* d_in, const int* in_sizes, int n_in,
                              void* d_out, int out_size, void* d_ws, size_t ws_size,
                              hipStream_t stream) {
    const float* x       = (const float*)d_in[0];
    const int*   ei      = (const int*)d_in[1];   // [2, E]: src then dst
    const float* ew      = (const float*)d_in[2];
    const int*   eli     = (const int*)d_in[3];   // [2, P]
    const float* w1_rel  = (const float*)d_in[4];
    const float* b1      = (const float*)d_in[5];
    const float* w1_root = (const float*)d_in[6];
    const float* w2_rel  = (const float*)d_in[7];
    const float* b2      = (const float*)d_in[8];
    const float* w2_root = (const float*)d_in[9];
    float* out = (float*)d_out;

    const int N = NN, E = NE, P = NP;
    const size_t hrow = (size_t)N * CH * sizeof(_Float16);   // 25.6 MB

    char* ws = (char*)d_ws;
    size_t off = 0;
    auto alloc = [&](size_t bytes) { char* p = ws + off; off = (off + bytes + 15) & ~(size_t)15; return p; };
    _Float16* xh  = (_Float16*)alloc(hrow);
    _Float16* hh  = (_Float16*)alloc(hrow);
    _Float16* zh  = (_Float16*)alloc(hrow);
    int* hist     = (int*)alloc((size_t)G1 * NB * 4);    // 1.6 MB
    int* totals   = (int*)alloc((size_t)NB * 4);
    int* base     = (int*)alloc((size_t)(NB + 1) * 4);
    int2* tmp     = (int2*)alloc((size_t)E * 8);         // 12.8 MB
    _Float16* w1t = (_Float16*)alloc((size_t)128 * 256 * 2);
    _Float16* w2t = (_Float16*)alloc((size_t)128 * 256 * 2);

    const int* src = ei;
    const int* dst = ei + E;

    // --- fused prep: cast + hist + weight transpose ---
    fused_prep_kernel<<<NCAST + G1 + 256, 256, 0, stream>>>(
        x, xh, dst, hist, w1_rel, w1_root, w2_rel, w2_root, w1t, w2t);

    // --- CSR-lite build (bucket-grouped edge list only) ---
    colscan_kernel<<<(NB + 3) / 4, 256, 0, stream>>>(hist, totals);
    scanB_kernel<<<1, 1024, 0, stream>>>(totals, base);
    bucket_scatter_kernel<<<G1, 256, 0, stream>>>(src, dst, ew, hist, base, tmp);

    // --- fused gather+layer, per bucket ---
    mega_kernel<true><<<NB, 256, 0, stream>>>(tmp, base, xh, w1t, b1, hh, N);
    mega_kernel<false><<<NB, 256, 0, stream>>>(tmp, base, hh, w2t, b2, zh, N);

    // --- decode ---
    {
        long threads = (long)P * 32;
        decode_kernel<<<(int)((threads + 255) / 256), 256, 0, stream>>>(zh, eli, eli + P, out, P);
    }
}

// Round 10
// 425.008 us; speedup vs baseline: 6.0590x; 6.0590x over previous
//
#include <hip/hip_runtime.h>

#define NN 100000
#define NE 1600000
#define NP 200000
#define CH 128
#define LK 264    // padded LDS row stride (fp16 elems)

#define BSH 6                    // 64 nodes per bucket
#define NB  1563                 // ceil(NN / 64)
#define G1  256                  // hist/scatter grid
#define EPB (NE / G1)            // 6250 edges per block
#define CAP3 4096                // finalize LDS edge capacity (mean bucket = 1024)
#define NCAST 6250               // cast blocks: NN*CH/8 / 256

typedef _Float16 f16x8 __attribute__((ext_vector_type(8)));
typedef _Float16 f16x4 __attribute__((ext_vector_type(4)));
typedef float f32x4 __attribute__((ext_vector_type(4)));

// ---- fused prep: [0,NCAST) cast x->fp16 | [NCAST,NCAST+G1) bucket hist | rest: weight prep ----
__global__ __launch_bounds__(256)
void fused_prep_kernel(const float* __restrict__ x, _Float16* __restrict__ xh,
                       const int* __restrict__ dst, int* __restrict__ hist,
                       const float* __restrict__ w1r, const float* __restrict__ w1o,
                       const float* __restrict__ w2r, const float* __restrict__ w2o,
                       _Float16* __restrict__ w1t, _Float16* __restrict__ w2t) {
    __shared__ int s_h[NB];
    const int bb = blockIdx.x, tid = threadIdx.x;
    if (bb < NCAST) {
        int i = bb * 256 + tid;   // i < 1.6M exactly
        const float4* p = (const float4*)x + (size_t)i * 2;
        float4 a = p[0], b = p[1];
        f16x8 o = { (_Float16)a.x, (_Float16)a.y, (_Float16)a.z, (_Float16)a.w,
                    (_Float16)b.x, (_Float16)b.y, (_Float16)b.z, (_Float16)b.w };
        *((f16x8*)xh + i) = o;
    } else if (bb < NCAST + G1) {
        int g = bb - NCAST;
        for (int i = tid; i < NB; i += 256) s_h[i] = 0;
        __syncthreads();
        int start = g * EPB, end = start + EPB;
        for (int e = start + tid; e < end; e += 256)
            atomicAdd(&s_h[dst[e] >> BSH], 1);
        __syncthreads();
        int* row = hist + (size_t)g * NB;
        for (int i = tid; i < NB; i += 256) row[i] = s_h[i];
    } else {
        int idx = (bb - NCAST - G1) * 256 + tid;   // < 65536
        int which = idx >> 15;
        int li = idx & 32767;
        int n = li >> 8, k = li & 255;
        const float* wr = which ? w2r : w1r;
        const float* wo = which ? w2o : w1o;
        _Float16* wt = which ? w2t : w1t;
        float v = (k < 128) ? wr[k * 128 + n] : wo[(k - 128) * 128 + n];
        wt[li] = (_Float16)v;
    }
}

// ---- column exclusive scan over g — one wave per bucket ----
__global__ __launch_bounds__(256)
void colscan_kernel(int* __restrict__ hist, int* __restrict__ totals) {
    int b = blockIdx.x * 4 + (threadIdx.x >> 6);
    if (b >= NB) return;
    int lane = threadIdx.x & 63;
    size_t base = (size_t)(lane * 4) * NB + b;
    int v0 = hist[base];
    int v1 = hist[base + NB];
    int v2 = hist[base + 2 * (size_t)NB];
    int v3 = hist[base + 3 * (size_t)NB];
    int s0 = v0, s1 = s0 + v1, s2 = s1 + v2, s3 = s2 + v3;
    int incl = s3;
#pragma unroll
    for (int off = 1; off < 64; off <<= 1) {
        int n = __shfl_up(incl, off, 64);
        if (lane >= off) incl += n;
    }
    int excl = incl - s3;
    hist[base] = excl;
    hist[base + NB] = excl + s0;
    hist[base + 2 * (size_t)NB] = excl + s1;
    hist[base + 3 * (size_t)NB] = excl + s2;
    if (lane == 63) totals[b] = incl;
}

// ---- exclusive scan of bucket totals -> base[NB+1] ----
__global__ __launch_bounds__(1024)
void scanB_kernel(const int* __restrict__ totals, int* __restrict__ base) {
    __shared__ int s[2048];
    int tid = threadIdx.x;
    for (int i = tid; i < 2048; i += 1024) s[i] = (i < NB) ? totals[i] : 0;
    __syncthreads();
    for (int off = 1; off < 2048; off <<= 1) {
        int i0 = tid, i1 = tid + 1024;
        int v0 = (i0 >= off) ? s[i0 - off] : 0;
        int v1 = (i1 >= off) ? s[i1 - off] : 0;
        __syncthreads();
        s[i0] += v0; s[i1] += v1;
        __syncthreads();
    }
    if (tid == 0) base[0] = 0;
    for (int i = tid; i < NB; i += 1024) base[i + 1] = s[i];
}

// ---- scatter edges into bucket regions; x = src | dst_local<<17, y = fp32 weight ----
__global__ __launch_bounds__(256)
void bucket_scatter_kernel(const int* __restrict__ src, const int* __restrict__ dst,
                           const float* __restrict__ ew, const int* __restrict__ hist,
                           const int* __restrict__ base, int2* __restrict__ tmp) {
    __shared__ int s_cur[NB];
    const int* row = hist + (size_t)blockIdx.x * NB;
    for (int i = threadIdx.x; i < NB; i += 256) s_cur[i] = base[i] + row[i];
    __syncthreads();
    int start = blockIdx.x * EPB, end = start + EPB;
    for (int e = start + threadIdx.x; e < end; e += 256) {
        int d = dst[e];
        int b = d >> BSH;
        int pos = atomicAdd(&s_cur[b], 1);
        tmp[pos] = make_int2(src[e] | ((d & 63) << 17), __float_as_int(ew[e]));
    }
}

// ---- finalize: per-bucket node-grouped csr + row_ptr ----
__global__ __launch_bounds__(256)
void bucket_finalize_kernel(const int2* __restrict__ tmp, const int* __restrict__ base,
                            int* __restrict__ row_ptr, int2* __restrict__ csr, int N) {
    __shared__ int2 s_e[CAP3];
    __shared__ int s_cnt[64], s_off[64];
    int b = blockIdx.x;
    int lo = base[b], hi = base[b + 1];
    int size = hi - lo;
    int nbase = b << BSH;
    int ncnt = min(64, N - nbase);
    int tid = threadIdx.x;
    if (tid < 64) s_cnt[tid] = 0;
    bool inlds = (size <= CAP3);
    __syncthreads();
    if (inlds) {
        for (int i = tid; i < size; i += 256) {
            int2 e = tmp[lo + i];
            s_e[i] = e;
            atomicAdd(&s_cnt[(e.x >> 17) & 63], 1);
        }
    } else {
        for (int i = tid; i < size; i += 256) {
            int2 e = tmp[lo + i];
            atomicAdd(&s_cnt[(e.x >> 17) & 63], 1);
        }
    }
    __syncthreads();
    if (tid == 0) {
        int run = 0;
        for (int i = 0; i < 64; i++) { int v = s_cnt[i]; s_off[i] = run; s_cnt[i] = run; run += v; }
    }
    __syncthreads();
    if (tid < ncnt) row_ptr[nbase + tid] = lo + s_off[tid];
    if (b == NB - 1 && tid == 0) row_ptr[N] = hi;
    if (inlds) {
        for (int i = tid; i < size; i += 256) {
            int2 e = s_e[i];
            int dl = (e.x >> 17) & 63;
            int p = atomicAdd(&s_cnt[dl], 1);
            csr[lo + p] = make_int2(e.x & 0x1FFFF, e.y);
        }
    } else {
        for (int i = tid; i < size; i += 256) {
            int2 e = tmp[lo + i];
            int dl = (e.x >> 17) & 63;
            int p = atomicAdd(&s_cnt[dl], 1);
            csr[lo + p] = make_int2(e.x & 0x1FFFF, e.y);
        }
    }
}

// ---- fused gather + MFMA layer: one block per 64-node bucket ----
// Phase 1: R7-style register gather (quarter-wave per node, fp32 chains) -> LDS A-tile
// Phase 2: stage self rows -> A-tile[., 128..255]
// Phase 3: MFMA 64x128 = [agg | self] @ Wt^T + b
template <bool RELU>
__global__ __launch_bounds__(256)
void gatherlayer_kernel(const _Float16* __restrict__ feat, const int* __restrict__ row_ptr,
                        const int2* __restrict__ csr, const _Float16* __restrict__ wt,
                        const float* __restrict__ bias, _Float16* __restrict__ out, int N) {
    __shared__ _Float16 atile[64][LK];   // 33792 B

    const int tid = threadIdx.x;
    const int nb = blockIdx.x << BSH;
    const int wave = tid >> 6;
    const int lane = tid & 63;
    const int q = lane >> 4;
    const int l16 = lane & 15;
    const int c8 = l16 << 3;

    // ---- phase 1: gather 16 nodes per wave, no LDS atomics ----
    for (int nn = 0; nn < 16; nn++) {
        int local_n = wave * 16 + nn;
        int node = nb + local_n;
        if (node >= N) break;                      // wave-uniform
        int r0 = row_ptr[node], r1 = row_ptr[node + 1];
        float acc[8] = {0.f, 0.f, 0.f, 0.f, 0.f, 0.f, 0.f, 0.f};
        int r = r0 + q;
        if (r < r1) {
            int2 e = csr[r];
            f16x8 v = *(const f16x8*)&feat[(size_t)e.x * CH + c8];
            for (r += 4; r < r1; r += 4) {
                int2 e2 = csr[r];
                f16x8 v2 = *(const f16x8*)&feat[(size_t)e2.x * CH + c8];
                float w = __int_as_float(e.y);
#pragma unroll
                for (int j = 0; j < 8; j++) acc[j] += w * (float)v[j];
                e = e2; v = v2;
            }
            float w = __int_as_float(e.y);
#pragma unroll
            for (int j = 0; j < 8; j++) acc[j] += w * (float)v[j];
        }
#pragma unroll
        for (int j = 0; j < 8; j++) {
            acc[j] += __shfl_xor(acc[j], 16, 64);
            acc[j] += __shfl_xor(acc[j], 32, 64);
        }
        if (q == 0) {
            float inv = 1.0f / fmaxf((float)(r1 - r0), 1.0f);
            f16x8 o;
#pragma unroll
            for (int j = 0; j < 8; j++) o[j] = (_Float16)(acc[j] * inv);
            *(f16x8*)&atile[local_n][c8] = o;
        }
    }

    // ---- phase 2: stage self rows (coalesced) ----
    for (int i = tid; i < 64 * 16; i += 256) {
        int rrow = i >> 4;
        int cc8 = (i & 15) << 3;
        int gn = nb + rrow;
        f16x8 v = {};
        if (gn < N) v = *(const f16x8*)&feat[(size_t)gn * CH + cc8];
        *(f16x8*)&atile[rrow][128 + cc8] = v;
    }
    __syncthreads();

    // ---- phase 3: MFMA ----
    const int quad = lane >> 4;
    f32x4 ac[4][2];
#pragma unroll
    for (int m = 0; m < 4; m++)
#pragma unroll
        for (int t = 0; t < 2; t++) ac[m][t] = (f32x4){0.f, 0.f, 0.f, 0.f};

    const int kq = quad * 8;
#pragma unroll
    for (int ks = 0; ks < 8; ks++) {
        int kbase = ks * 32 + kq;
        f16x8 bf[2];
#pragma unroll
        for (int t = 0; t < 2; t++) {
            int n = wave * 32 + t * 16 + l16;
            bf[t] = *(const f16x8*)&wt[(size_t)n * 256 + kbase];
        }
#pragma unroll
        for (int m = 0; m < 4; m++) {
            f16x8 af = *(const f16x8*)&atile[m * 16 + l16][kbase];
            ac[m][0] = __builtin_amdgcn_mfma_f32_16x16x32_f16(af, bf[0], ac[m][0], 0, 0, 0);
            ac[m][1] = __builtin_amdgcn_mfma_f32_16x16x32_f16(af, bf[1], ac[m][1], 0, 0, 0);
        }
    }

    float bv[2];
    bv[0] = bias[wave * 32 + l16];
    bv[1] = bias[wave * 32 + 16 + l16];

#pragma unroll
    for (int m = 0; m < 4; m++) {
#pragma unroll
        for (int r = 0; r < 4; r++) {
            int node = nb + m * 16 + quad * 4 + r;
            if (node >= N) continue;
#pragma unroll
            for (int t = 0; t < 2; t++) {
                float v = ac[m][t][r] + bv[t];
                if (RELU) v = fmaxf(v, 0.f);
                out[(size_t)node * CH + wave * 32 + t * 16 + l16] = (_Float16)v;
            }
        }
    }
}

// ---- decode: half-wave per pair, f16x4 per lane ----
__global__ void decode_kernel(const _Float16* __restrict__ z,
                              const int* __restrict__ ps,
                              const int* __restrict__ pd,
                              float* __restrict__ out, int P) {
    long tid = (long)blockIdx.x * blockDim.x + threadIdx.x;
    int p = (int)(tid >> 5);
    int lane = (int)(tid & 31);
    if (p >= P) return;
    int s = ps[p], d = pd[p];
    f16x4 a = *(const f16x4*)&z[(size_t)s * CH + lane * 4];
    f16x4 b = *(const f16x4*)&z[(size_t)d * CH + lane * 4];
    float v = (float)a[0] * (float)b[0] + (float)a[1] * (float)b[1]
            + (float)a[2] * (float)b[2] + (float)a[3] * (float)b[3];
#pragma unroll
    for (int off = 16; off > 0; off >>= 1) v += __shfl_xor(v, off, 64);
    if (lane == 0) out[p] = v * 0.08838834764831845f;  // 1/sqrt(128)
}

extern "C" void kernel_launch(void* const* d_in, const int* in_sizes, int n_in,
                              void* d_out, int out_size, void* d_ws, size_t ws_size,
                              hipStream_t stream) {
    const float* x       = (const float*)d_in[0];
    const int*   ei      = (const int*)d_in[1];   // [2, E]: src then dst
    const float* ew      = (const float*)d_in[2];
    const int*   eli     = (const int*)d_in[3];   // [2, P]
    const float* w1_rel  = (const float*)d_in[4];
    const float* b1      = (const float*)d_in[5];
    const float* w1_root = (const float*)d_in[6];
    const float* w2_rel  = (const float*)d_in[7];
    const float* b2      = (const float*)d_in[8];
    const float* w2_root = (const float*)d_in[9];
    float* out = (float*)d_out;

    const int N = NN, E = NE, P = NP;
    const size_t hrow = (size_t)N * CH * sizeof(_Float16);   // 25.6 MB

    char* ws = (char*)d_ws;
    size_t off = 0;
    auto alloc = [&](size_t bytes) { char* p = ws + off; off = (off + bytes + 15) & ~(size_t)15; return p; };
    _Float16* xh  = (_Float16*)alloc(hrow);
    _Float16* hh  = (_Float16*)alloc(hrow);
    _Float16* zh  = (_Float16*)alloc(hrow);
    int* hist     = (int*)alloc((size_t)G1 * NB * 4);    // 1.6 MB
    int* totals   = (int*)alloc((size_t)NB * 4);
    int* base     = (int*)alloc((size_t)(NB + 1) * 4);
    int* row_ptr  = (int*)alloc((size_t)(N + 1) * 4);
    int2* tmp     = (int2*)alloc((size_t)E * 8);         // 12.8 MB
    int2* csr     = (int2*)alloc((size_t)E * 8);         // 12.8 MB
    _Float16* w1t = (_Float16*)alloc((size_t)128 * 256 * 2);
    _Float16* w2t = (_Float16*)alloc((size_t)128 * 256 * 2);

    const int* src = ei;
    const int* dst = ei + E;

    // --- fused prep: cast + hist + weight transpose ---
    fused_prep_kernel<<<NCAST + G1 + 256, 256, 0, stream>>>(
        x, xh, dst, hist, w1_rel, w1_root, w2_rel, w2_root, w1t, w2t);

    // --- CSR build (atomic-free bucketed counting sort) ---
    colscan_kernel<<<(NB + 3) / 4, 256, 0, stream>>>(hist, totals);
    scanB_kernel<<<1, 1024, 0, stream>>>(totals, base);
    bucket_scatter_kernel<<<G1, 256, 0, stream>>>(src, dst, ew, hist, base, tmp);
    bucket_finalize_kernel<<<NB, 256, 0, stream>>>(tmp, base, row_ptr, csr, N);

    // --- fused gather + layer (per 64-node bucket) ---
    gatherlayer_kernel<true><<<NB, 256, 0, stream>>>(xh, row_ptr, csr, w1t, b1, hh, N);
    gatherlayer_kernel<false><<<NB, 256, 0, stream>>>(hh, row_ptr, csr, w2t, b2, zh, N);

    // --- decode ---
    {
        long threads = (long)P * 32;
        decode_kernel<<<(int)((threads + 255) / 256), 256, 0, stream>>>(zh, eli, eli + P, out, P);
    }
}

// Round 11
// 377.038 us; speedup vs baseline: 6.8298x; 1.1272x over previous
//
#include <hip/hip_runtime.h>

#define NN 100000
#define NE 1600000
#define NP 200000
#define CH 128
#define LK 264    // padded LDS row stride (fp16 elems)

#define BSH 6                    // 64 nodes per bucket
#define NB  1563                 // ceil(NN / 64)
#define G1  256                  // hist/scatter grid
#define EPB (NE / G1)            // 6250 edges per block
#define CAP3 4096                // finalize LDS edge capacity (mean bucket = 1024)
#define NCAST 6250               // cast blocks: NN*CH/8 / 256

typedef _Float16 f16x8 __attribute__((ext_vector_type(8)));
typedef _Float16 f16x4 __attribute__((ext_vector_type(4)));
typedef float f32x4 __attribute__((ext_vector_type(4)));

// ---- fused prep: [0,NCAST) cast x->fp16 | [NCAST,NCAST+G1) bucket hist | rest: weight prep ----
__global__ __launch_bounds__(256)
void fused_prep_kernel(const float* __restrict__ x, _Float16* __restrict__ xh,
                       const int* __restrict__ dst, int* __restrict__ hist,
                       const float* __restrict__ w1r, const float* __restrict__ w1o,
                       const float* __restrict__ w2r, const float* __restrict__ w2o,
                       _Float16* __restrict__ w1t, _Float16* __restrict__ w2t) {
    __shared__ int s_h[NB];
    const int bb = blockIdx.x, tid = threadIdx.x;
    if (bb < NCAST) {
        int i = bb * 256 + tid;   // i < 1.6M exactly
        const float4* p = (const float4*)x + (size_t)i * 2;
        float4 a = p[0], b = p[1];
        f16x8 o = { (_Float16)a.x, (_Float16)a.y, (_Float16)a.z, (_Float16)a.w,
                    (_Float16)b.x, (_Float16)b.y, (_Float16)b.z, (_Float16)b.w };
        *((f16x8*)xh + i) = o;
    } else if (bb < NCAST + G1) {
        int g = bb - NCAST;
        for (int i = tid; i < NB; i += 256) s_h[i] = 0;
        __syncthreads();
        int start = g * EPB, end = start + EPB;
        for (int e = start + tid; e < end; e += 256)
            atomicAdd(&s_h[dst[e] >> BSH], 1);
        __syncthreads();
        int* row = hist + (size_t)g * NB;
        for (int i = tid; i < NB; i += 256) row[i] = s_h[i];
    } else {
        int idx = (bb - NCAST - G1) * 256 + tid;   // < 65536
        int which = idx >> 15;
        int li = idx & 32767;
        int n = li >> 8, k = li & 255;
        const float* wr = which ? w2r : w1r;
        const float* wo = which ? w2o : w1o;
        _Float16* wt = which ? w2t : w1t;
        float v = (k < 128) ? wr[k * 128 + n] : wo[(k - 128) * 128 + n];
        wt[li] = (_Float16)v;
    }
}

// ---- column exclusive scan over g — one wave per bucket ----
__global__ __launch_bounds__(256)
void colscan_kernel(int* __restrict__ hist, int* __restrict__ totals) {
    int b = blockIdx.x * 4 + (threadIdx.x >> 6);
    if (b >= NB) return;
    int lane = threadIdx.x & 63;
    size_t base = (size_t)(lane * 4) * NB + b;
    int v0 = hist[base];
    int v1 = hist[base + NB];
    int v2 = hist[base + 2 * (size_t)NB];
    int v3 = hist[base + 3 * (size_t)NB];
    int s0 = v0, s1 = s0 + v1, s2 = s1 + v2, s3 = s2 + v3;
    int incl = s3;
#pragma unroll
    for (int off = 1; off < 64; off <<= 1) {
        int n = __shfl_up(incl, off, 64);
        if (lane >= off) incl += n;
    }
    int excl = incl - s3;
    hist[base] = excl;
    hist[base + NB] = excl + s0;
    hist[base + 2 * (size_t)NB] = excl + s1;
    hist[base + 3 * (size_t)NB] = excl + s2;
    if (lane == 63) totals[b] = incl;
}

// ---- exclusive scan of bucket totals -> base[NB+1] ----
__global__ __launch_bounds__(1024)
void scanB_kernel(const int* __restrict__ totals, int* __restrict__ base) {
    __shared__ int s[2048];
    int tid = threadIdx.x;
    for (int i = tid; i < 2048; i += 1024) s[i] = (i < NB) ? totals[i] : 0;
    __syncthreads();
    for (int off = 1; off < 2048; off <<= 1) {
        int i0 = tid, i1 = tid + 1024;
        int v0 = (i0 >= off) ? s[i0 - off] : 0;
        int v1 = (i1 >= off) ? s[i1 - off] : 0;
        __syncthreads();
        s[i0] += v0; s[i1] += v1;
        __syncthreads();
    }
    if (tid == 0) base[0] = 0;
    for (int i = tid; i < NB; i += 1024) base[i + 1] = s[i];
}

// ---- scatter edges into bucket regions; x = src | dst_local<<17, y = fp32 weight ----
__global__ __launch_bounds__(256)
void bucket_scatter_kernel(const int* __restrict__ src, const int* __restrict__ dst,
                           const float* __restrict__ ew, const int* __restrict__ hist,
                           const int* __restrict__ base, int2* __restrict__ tmp) {
    __shared__ int s_cur[NB];
    const int* row = hist + (size_t)blockIdx.x * NB;
    for (int i = threadIdx.x; i < NB; i += 256) s_cur[i] = base[i] + row[i];
    __syncthreads();
    int start = blockIdx.x * EPB, end = start + EPB;
    for (int e = start + threadIdx.x; e < end; e += 256) {
        int d = dst[e];
        int b = d >> BSH;
        int pos = atomicAdd(&s_cur[b], 1);
        tmp[pos] = make_int2(src[e] | ((d & 63) << 17), __float_as_int(ew[e]));
    }
}

// ---- finalize: per-bucket node-grouped csr + row_ptr ----
__global__ __launch_bounds__(256)
void bucket_finalize_kernel(const int2* __restrict__ tmp, const int* __restrict__ base,
                            int* __restrict__ row_ptr, int2* __restrict__ csr, int N) {
    __shared__ int2 s_e[CAP3];
    __shared__ int s_cnt[64], s_off[64];
    int b = blockIdx.x;
    int lo = base[b], hi = base[b + 1];
    int size = hi - lo;
    int nbase = b << BSH;
    int ncnt = min(64, N - nbase);
    int tid = threadIdx.x;
    if (tid < 64) s_cnt[tid] = 0;
    bool inlds = (size <= CAP3);
    __syncthreads();
    if (inlds) {
        for (int i = tid; i < size; i += 256) {
            int2 e = tmp[lo + i];
            s_e[i] = e;
            atomicAdd(&s_cnt[(e.x >> 17) & 63], 1);
        }
    } else {
        for (int i = tid; i < size; i += 256) {
            int2 e = tmp[lo + i];
            atomicAdd(&s_cnt[(e.x >> 17) & 63], 1);
        }
    }
    __syncthreads();
    if (tid == 0) {
        int run = 0;
        for (int i = 0; i < 64; i++) { int v = s_cnt[i]; s_off[i] = run; s_cnt[i] = run; run += v; }
    }
    __syncthreads();
    if (tid < ncnt) row_ptr[nbase + tid] = lo + s_off[tid];
    if (b == NB - 1 && tid == 0) row_ptr[N] = hi;
    if (inlds) {
        for (int i = tid; i < size; i += 256) {
            int2 e = s_e[i];
            int dl = (e.x >> 17) & 63;
            int p = atomicAdd(&s_cnt[dl], 1);
            csr[lo + p] = make_int2(e.x & 0x1FFFF, e.y);
        }
    } else {
        for (int i = tid; i < size; i += 256) {
            int2 e = tmp[lo + i];
            int dl = (e.x >> 17) & 63;
            int p = atomicAdd(&s_cnt[dl], 1);
            csr[lo + p] = make_int2(e.x & 0x1FFFF, e.y);
        }
    }
}

// ---- fused gather + MFMA layer: one block (512 thr, 8 waves) per 64-node bucket ----
// Phase 1: register gather, each wave handles 8 nodes (quarter-wave per node)
// Phase 2: stage self rows -> A-tile[., 128..255]
// Phase 3: MFMA 64x128 = [agg | self] @ Wt^T + b; wave w owns 16 output cols
template <bool RELU>
__global__ __launch_bounds__(512)
void gatherlayer_kernel(const _Float16* __restrict__ feat, const int* __restrict__ row_ptr,
                        const int2* __restrict__ csr, const _Float16* __restrict__ wt,
                        const float* __restrict__ bias, _Float16* __restrict__ out, int N) {
    __shared__ _Float16 atile[64][LK];   // 33792 B -> 4 blocks/CU = 32 waves/CU

    const int tid = threadIdx.x;
    const int nb = blockIdx.x << BSH;
    const int wave = tid >> 6;          // 0..7
    const int lane = tid & 63;
    const int q = lane >> 4;
    const int l16 = lane & 15;
    const int c8 = l16 << 3;

    // ---- phase 1: gather 8 nodes per wave, fp32 register chains, no LDS atomics ----
    for (int nn = 0; nn < 8; nn++) {
        int local_n = wave * 8 + nn;
        int node = nb + local_n;
        if (node >= N) break;                      // wave-uniform
        int r0 = row_ptr[node], r1 = row_ptr[node + 1];
        float acc[8] = {0.f, 0.f, 0.f, 0.f, 0.f, 0.f, 0.f, 0.f};
        int r = r0 + q;
        if (r < r1) {
            int2 e = csr[r];
            f16x8 v = *(const f16x8*)&feat[(size_t)e.x * CH + c8];
            for (r += 4; r < r1; r += 4) {
                int2 e2 = csr[r];
                f16x8 v2 = *(const f16x8*)&feat[(size_t)e2.x * CH + c8];
                float w = __int_as_float(e.y);
#pragma unroll
                for (int j = 0; j < 8; j++) acc[j] += w * (float)v[j];
                e = e2; v = v2;
            }
            float w = __int_as_float(e.y);
#pragma unroll
            for (int j = 0; j < 8; j++) acc[j] += w * (float)v[j];
        }
#pragma unroll
        for (int j = 0; j < 8; j++) {
            acc[j] += __shfl_xor(acc[j], 16, 64);
            acc[j] += __shfl_xor(acc[j], 32, 64);
        }
        if (q == 0) {
            float inv = 1.0f / fmaxf((float)(r1 - r0), 1.0f);
            f16x8 o;
#pragma unroll
            for (int j = 0; j < 8; j++) o[j] = (_Float16)(acc[j] * inv);
            *(f16x8*)&atile[local_n][c8] = o;
        }
    }

    // ---- phase 2: stage self rows (coalesced) ----
    for (int i = tid; i < 64 * 16; i += 512) {
        int rrow = i >> 4;
        int cc8 = (i & 15) << 3;
        int gn = nb + rrow;
        f16x8 v = {};
        if (gn < N) v = *(const f16x8*)&feat[(size_t)gn * CH + cc8];
        *(f16x8*)&atile[rrow][128 + cc8] = v;
    }
    __syncthreads();

    // ---- phase 3: MFMA; wave w -> output cols w*16..w*16+15 ----
    f32x4 ac[4];
#pragma unroll
    for (int m = 0; m < 4; m++) ac[m] = (f32x4){0.f, 0.f, 0.f, 0.f};

    const int ncol = wave * 16 + l16;
    const int kq = q * 8;
#pragma unroll
    for (int ks = 0; ks < 8; ks++) {
        int kbase = ks * 32 + kq;
        f16x8 bf = *(const f16x8*)&wt[(size_t)ncol * 256 + kbase];
#pragma unroll
        for (int m = 0; m < 4; m++) {
            f16x8 af = *(const f16x8*)&atile[m * 16 + l16][kbase];
            ac[m] = __builtin_amdgcn_mfma_f32_16x16x32_f16(af, bf, ac[m], 0, 0, 0);
        }
    }

    float bv = bias[ncol];
#pragma unroll
    for (int m = 0; m < 4; m++) {
#pragma unroll
        for (int r = 0; r < 4; r++) {
            int node = nb + m * 16 + q * 4 + r;
            if (node >= N) continue;
            float v = ac[m][r] + bv;
            if (RELU) v = fmaxf(v, 0.f);
            out[(size_t)node * CH + ncol] = (_Float16)v;
        }
    }
}

// ---- decode: half-wave per pair, f16x4 per lane ----
__global__ void decode_kernel(const _Float16* __restrict__ z,
                              const int* __restrict__ ps,
                              const int* __restrict__ pd,
                              float* __restrict__ out, int P) {
    long tid = (long)blockIdx.x * blockDim.x + threadIdx.x;
    int p = (int)(tid >> 5);
    int lane = (int)(tid & 31);
    if (p >= P) return;
    int s = ps[p], d = pd[p];
    f16x4 a = *(const f16x4*)&z[(size_t)s * CH + lane * 4];
    f16x4 b = *(const f16x4*)&z[(size_t)d * CH + lane * 4];
    float v = (float)a[0] * (float)b[0] + (float)a[1] * (float)b[1]
            + (float)a[2] * (float)b[2] + (float)a[3] * (float)b[3];
#pragma unroll
    for (int off = 16; off > 0; off >>= 1) v += __shfl_xor(v, off, 64);
    if (lane == 0) out[p] = v * 0.08838834764831845f;  // 1/sqrt(128)
}

extern "C" void kernel_launch(void* const* d_in, const int* in_sizes, int n_in,
                              void* d_out, int out_size, void* d_ws, size_t ws_size,
                              hipStream_t stream) {
    const float* x       = (const float*)d_in[0];
    const int*   ei      = (const int*)d_in[1];   // [2, E]: src then dst
    const float* ew      = (const float*)d_in[2];
    const int*   eli     = (const int*)d_in[3];   // [2, P]
    const float* w1_rel  = (const float*)d_in[4];
    const float* b1      = (const float*)d_in[5];
    const float* w1_root = (const float*)d_in[6];
    const float* w2_rel  = (const float*)d_in[7];
    const float* b2      = (const float*)d_in[8];
    const float* w2_root = (const float*)d_in[9];
    float* out = (float*)d_out;

    const int N = NN, E = NE, P = NP;
    const size_t hrow = (size_t)N * CH * sizeof(_Float16);   // 25.6 MB

    char* ws = (char*)d_ws;
    size_t off = 0;
    auto alloc = [&](size_t bytes) { char* p = ws + off; off = (off + bytes + 15) & ~(size_t)15; return p; };
    _Float16* xh  = (_Float16*)alloc(hrow);
    _Float16* hh  = (_Float16*)alloc(hrow);
    _Float16* zh  = (_Float16*)alloc(hrow);
    int* hist     = (int*)alloc((size_t)G1 * NB * 4);    // 1.6 MB
    int* totals   = (int*)alloc((size_t)NB * 4);
    int* base     = (int*)alloc((size_t)(NB + 1) * 4);
    int* row_ptr  = (int*)alloc((size_t)(N + 1) * 4);
    int2* tmp     = (int2*)alloc((size_t)E * 8);         // 12.8 MB
    int2* csr     = (int2*)alloc((size_t)E * 8);         // 12.8 MB
    _Float16* w1t = (_Float16*)alloc((size_t)128 * 256 * 2);
    _Float16* w2t = (_Float16*)alloc((size_t)128 * 256 * 2);

    const int* src = ei;
    const int* dst = ei + E;

    // --- fused prep: cast + hist + weight transpose ---
    fused_prep_kernel<<<NCAST + G1 + 256, 256, 0, stream>>>(
        x, xh, dst, hist, w1_rel, w1_root, w2_rel, w2_root, w1t, w2t);

    // --- CSR build (atomic-free bucketed counting sort) ---
    colscan_kernel<<<(NB + 3) / 4, 256, 0, stream>>>(hist, totals);
    scanB_kernel<<<1, 1024, 0, stream>>>(totals, base);
    bucket_scatter_kernel<<<G1, 256, 0, stream>>>(src, dst, ew, hist, base, tmp);
    bucket_finalize_kernel<<<NB, 256, 0, stream>>>(tmp, base, row_ptr, csr, N);

    // --- fused gather + layer (per 64-node bucket, 512 threads) ---
    gatherlayer_kernel<true><<<NB, 512, 0, stream>>>(xh, row_ptr, csr, w1t, b1, hh, N);
    gatherlayer_kernel<false><<<NB, 512, 0, stream>>>(hh, row_ptr, csr, w2t, b2, zh, N);

    // --- decode ---
    {
        long threads = (long)P * 32;
        decode_kernel<<<(int)((threads + 255) / 256), 256, 0, stream>>>(zh, eli, eli + P, out, P);
    }
}